// Round 10
// baseline (360.729 us; speedup 1.0000x reference)
//
#include <hip/hip_runtime.h>
#include <math.h>

#define N_NODES 100000
#define N_EDGES 3200000
#define N_GRAPHS 64
#define BW 128                               // nodes per bucket
#define LSH 7
#define LMASK 127u
#define NBUCK ((N_NODES + BW - 1) / BW)      // 782
#define CHUNK_E 8192
#define NCHUNK ((N_EDGES + CHUNK_E - 1) / CHUNK_E)  // 391
#define POOL_SCALE 1024.0f
#define POOL_INV (1.0f / 1024.0f)
#define SENT ((unsigned int)N_NODES << LSH)  // sentinel edge -> ac[N_NODES] == (0,0)

// ---- node-level degree: global atomics (deg = 400KB, L2-resident, ~32 hits/ctr) ----
__global__ void k_deg(const int* __restrict__ dst, unsigned int* __restrict__ deg) {
    int stride = gridDim.x * blockDim.x;
    for (int e = blockIdx.x * blockDim.x + threadIdx.x; e < N_EDGES; e += stride)
        atomicAdd(&deg[dst[e]], 1u);
}

// ---- dinv/s from deg + per-bucket totals (replaces k_count and k_dinv) ----
__global__ void k_base(const unsigned int* __restrict__ deg, const float* __restrict__ x,
                       float* __restrict__ dinv, float* __restrict__ s, float2* __restrict__ ac,
                       unsigned int* __restrict__ totals) {
    __shared__ unsigned int w0sum;
    int b = blockIdx.x, t = threadIdx.x;
    int n = b * BW + t;
    unsigned int d = (n < N_NODES) ? deg[n] : 0u;
    if (n < N_NODES) {
        float di = 1.0f / sqrtf((float)(d + 1u));   // +1 self-loop
        dinv[n] = di;
        s[n] = x[n] * di;
    }
    if (n == 0) ac[N_NODES] = make_float2(0.0f, 0.0f);  // sentinel for k_l2 padded slots
    unsigned int v = d;
    v += __shfl_xor(v, 1);  v += __shfl_xor(v, 2);  v += __shfl_xor(v, 4);
    v += __shfl_xor(v, 8);  v += __shfl_xor(v, 16); v += __shfl_xor(v, 32);
    if (t == 0) w0sum = v;
    __syncthreads();
    if (t == 64) totals[b] = v + w0sum;
}

// ---- exclusive scan of bucket totals -> base (1 block) ----
__global__ void k_scanb(const unsigned int* __restrict__ totals, unsigned int* __restrict__ base) {
    __shared__ unsigned int sd[1024];
    int t = threadIdx.x;
    unsigned int v = (t < NBUCK) ? totals[t] : 0u;
    sd[t] = v;
    __syncthreads();
    for (int o = 1; o < 1024; o <<= 1) {
        unsigned int tv = (t >= o) ? sd[t - o] : 0u;
        __syncthreads();
        sd[t] += tv;
        __syncthreads();
    }
    if (t < NBUCK) base[t] = sd[t] - v;
    if (t == 0) base[NBUCK] = N_EDGES;
}

// ---- place edges into buckets; chunk SELF-RESERVES its per-bucket ranges ----
// (replaces the counts matrix + k_scanc: LDS hist -> one global fetch_add per
// nonzero bucket -> scatter via LDS cursors). Bucket-confined writes keep the
// active write set at ~782 moving pointers — round-2 post-mortem: do NOT
// replace with per-node cursors (per-XCD L2 thrash, 197MB WRITE_SIZE).
__global__ void k_part(const int* __restrict__ src, const int* __restrict__ dst,
                       const unsigned int* __restrict__ base, unsigned int* __restrict__ gcur,
                       unsigned int* __restrict__ packed) {
    __shared__ unsigned int hist[NBUCK];
    __shared__ unsigned int sstart[NBUCK];
    for (int i = threadIdx.x; i < NBUCK; i += blockDim.x) hist[i] = 0u;
    __syncthreads();
    int e0 = blockIdx.x * CHUNK_E;
    int e1 = min(e0 + CHUNK_E, N_EDGES);
    for (int e = e0 + threadIdx.x; e < e1; e += blockDim.x)
        atomicAdd(&hist[dst[e] >> LSH], 1u);
    __syncthreads();
    for (int i = threadIdx.x; i < NBUCK; i += blockDim.x) {
        unsigned int h = hist[i];
        sstart[i] = h ? (base[i] + atomicAdd(&gcur[i], h)) : 0u;
        hist[i] = 0u;                       // reuse as scatter cursor
    }
    __syncthreads();
    for (int e = e0 + threadIdx.x; e < e1; e += blockDim.x) {
        int d = dst[e];
        int bk = d >> LSH;
        unsigned int pos = sstart[bk] + atomicAdd(&hist[bk], 1u);
        packed[pos] = ((unsigned int)src[e] << LSH) | ((unsigned int)d & LMASK);
    }
}

// ---- per-bucket exact dst sort -> packed2 + rowstart, FUSED with layer 1 ----
// During the histogram pass we also accumulate fsum[d] += s[src] (native
// ds_add_f32) — the layer-1 neighbor sum — and emit ac[n] with rowstart.
// Deletes the separate k_l1 pass (12.8MB packed2 re-read). Summation order is
// atomic-nondeterministic, same as the edge order already was.
__global__ void k_sort(const unsigned int* __restrict__ base, const unsigned int* __restrict__ packed,
                       unsigned int* __restrict__ packed2, unsigned int* __restrict__ rowstart,
                       const float* __restrict__ dinv, const float* __restrict__ s,
                       float2* __restrict__ ac) {
    __shared__ unsigned int hist[BW];
    __shared__ unsigned int scan[BW];
    __shared__ unsigned int cur[BW];
    __shared__ float fsum[BW];
    int b = blockIdx.x;
    unsigned int e0 = base[b], e1 = base[b + 1];
    if (threadIdx.x < BW) { hist[threadIdx.x] = 0u; fsum[threadIdx.x] = 0.0f; }
    __syncthreads();
    for (unsigned int e = e0 + threadIdx.x; e < e1; e += blockDim.x) {
        unsigned int p = packed[e];
        unsigned int d = p & LMASK;
        atomicAdd(&hist[d], 1u);
        atomicAdd(&fsum[d], s[p >> LSH]);   // layer-1 neighbor sum (ds_add_f32)
    }
    __syncthreads();
    if (threadIdx.x < BW) scan[threadIdx.x] = hist[threadIdx.x];
    __syncthreads();
    for (int o = 1; o < BW; o <<= 1) {
        unsigned int v = 0u;
        if (threadIdx.x < BW && threadIdx.x >= (unsigned)o) v = scan[threadIdx.x - o];
        __syncthreads();
        if (threadIdx.x < BW && threadIdx.x >= (unsigned)o) scan[threadIdx.x] += v;
        __syncthreads();
    }
    if (threadIdx.x < BW) {
        unsigned int excl = scan[threadIdx.x] - hist[threadIdx.x];
        cur[threadIdx.x] = excl;
        rowstart[b * BW + threadIdx.x] = e0 + excl;
        int n = b * BW + threadIdx.x;
        if (n < N_NODES) {
            float di = dinv[n];
            ac[n] = make_float2(di, di * di * (fsum[threadIdx.x] + s[n]));
        }
    }
    __syncthreads();
    for (unsigned int e = e0 + threadIdx.x; e < e1; e += blockDim.x) {
        unsigned int p = packed[e];
        unsigned int pos = e0 + atomicAdd(&cur[p & LMASK], 1u);
        packed2[pos] = p;
    }
}

// ---- graph node counts via binary search (no atomics) ----
__global__ void k_gcnt(const int* __restrict__ batch, float* __restrict__ gcnt) {
    __shared__ int lb[N_GRAPHS + 1];
    int b = threadIdx.x;
    if (b <= N_GRAPHS) {
        int lo = 0, hi = N_NODES;
        while (lo < hi) {
            int mid = (lo + hi) >> 1;
            if (batch[mid] < b) lo = mid + 1; else hi = mid;
        }
        lb[b] = lo;
    }
    __syncthreads();
    if (b < N_GRAPHS) gcnt[b] = (float)(lb[b + 1] - lb[b]);
}

// ---- layer 2: one 64-lane wave per node, lane j = column j ----
// ROUND-5 KERNEL VERBATIM — proven 36 VGPR, zero scratch, 54-56 µs, FETCH 10 MB.
// DO NOT EDIT THIS KERNEL'S BODY: rounds 6/7/8 each made small changes (packed
// math; prefetch+4 accumulators; even a 2-accumulator algebra tweak) and ALL
// tipped the register allocator into demoting w2c[32] to scratch — 100-310 MB
// of HBM scratch traffic, 2-3x kernel slowdown, and graph-replay-wide damage.
// The codegen sits exactly on a register-bucket boundary.
// This structure is ~at its LDS-broadcast floor anyway (~16 b128 uniform-addr
// reads + staging + Hrow matvec ≈ 50 µs of LDS pipe — measured 54-56).
#define NPW 8

#define EDGE_PAIR(P) { \
    float4 q_ = Epair4[(P)]; \
    H += fmaxf(fmaf(q_.y, w1j, q_.x * b1j), 0.0f); \
    H += fmaxf(fmaf(q_.w, w1j, q_.z * b1j), 0.0f); }

#define BLOCK16(P0) { \
    EDGE_PAIR((P0) + 0) EDGE_PAIR((P0) + 1) EDGE_PAIR((P0) + 2) EDGE_PAIR((P0) + 3) \
    EDGE_PAIR((P0) + 4) EDGE_PAIR((P0) + 5) EDGE_PAIR((P0) + 6) EDGE_PAIR((P0) + 7) }

__global__ __launch_bounds__(256, 6)
void k_l2(const unsigned int* __restrict__ rowstart, const unsigned int* __restrict__ packed2,
          const float2* __restrict__ ac,
          const float* __restrict__ W1, const float* __restrict__ b1,
          const float* __restrict__ W2, const float* __restrict__ b2,
          const int* __restrict__ batch, int* __restrict__ gsumi) {
    __shared__ float Hrow[4][64];    // one 64-float row per wave; wave-private
    __shared__ float4 Ebuf[4][32];   // 64 (ax,ay) pairs per wave, read as float4 (2 edges/read)
    const int lane = threadIdx.x & 63;
    const int wv   = threadIdx.x >> 6;
    const int k    = lane & 31;     // output column for matvec/pool
    const int jh   = lane >> 5;     // which half of the 64-wide hidden dim this lane reduces
    const int j0   = jh * 32;

    const float w1j = W1[lane];
    const float b1j = b1[lane];
    const float b2k = b2[k];
    float w2c[32];
#pragma unroll
    for (int j = 0; j < 32; j++) w2c[j] = W2[(j0 + j) * 32 + k];

    float4* Epair4 = &Ebuf[wv][0];                 // wave-uniform base
    float2* Ewr    = (float2*)&Ebuf[wv][0];        // per-lane write slot

    int n0 = (blockIdx.x * 4 + wv) * NPW;
    float racc = 0.0f;
    int curg = -1;
    for (int i = 0; i < NPW; i++) {
        int n = n0 + i;
        if (n >= N_NODES) break;
        unsigned int rs = rowstart[n], re = rowstart[n + 1];
        float2 acn = ac[n];
        // self-loop contribution
        float H = fmaxf(fmaf(acn.y, w1j, acn.x * b1j), 0.0f);
        unsigned int e0 = rs;
        // full 64-slot batches (deg >= 64, rare at Poisson(32))
        while (e0 + 64u <= re) {
            unsigned int p = packed2[e0 + lane];     // all lanes valid
            Ewr[lane] = ac[p >> LSH];                // gather -> wave-private LDS (ds_write_b64)
            BLOCK16(0) BLOCK16(8) BLOCK16(16) BLOCK16(24)
            e0 += 64u;
        }
        unsigned int rem = re - e0;                  // 0..63
        if (rem) {
            unsigned int idx = e0 + lane;
            unsigned int p = SENT;                   // sentinel -> ac[N_NODES] == (0,0)
            if (idx < re) p = packed2[idx];          // exec-masked load, no OOB
            Ewr[lane] = ac[p >> LSH];
            switch ((rem + 15u) >> 4) {              // 1..4 blocks of 16 slots (8 pairs)
                case 4: BLOCK16(24); [[fallthrough]];
                case 3: BLOCK16(16); [[fallthrough]];
                case 2: BLOCK16(8);  [[fallthrough]];
                case 1: BLOCK16(0);
            }
        }
        // matvec: out_k = relu(dinv_n * (H . W2[:,k]) + b2[k])
        Hrow[wv][lane] = H;     // same-wave ds ordering: visible to this wave without barrier
        float accv = 0.0f;
#pragma unroll
        for (int jj = 0; jj < 8; jj++) {
            float4 hv = *(const float4*)&Hrow[wv][j0 + 4 * jj];
            accv += hv.x * w2c[4 * jj + 0] + hv.y * w2c[4 * jj + 1]
                  + hv.z * w2c[4 * jj + 2] + hv.w * w2c[4 * jj + 3];
        }
        accv += __shfl_xor(accv, 32);   // combine half-partials (width 64)
        float v = fmaxf(fmaf(acn.x, accv, b2k), 0.0f);
        int gb = batch[n];               // wave-uniform scalar load
        if (gb != curg) {
            if (curg >= 0 && jh == 0)
                atomicAdd(&gsumi[curg * 32 + k], __float2int_rn(racc * POOL_SCALE));
            racc = 0.0f; curg = gb;
        }
        racc += v;
    }
    if (curg >= 0 && jh == 0)
        atomicAdd(&gsumi[curg * 32 + k], __float2int_rn(racc * POOL_SCALE));
}

// ---- readout ----
__global__ void k_readout(const int* __restrict__ gsumi, const float* __restrict__ gcnt,
                          const float* __restrict__ Wfc, const float* __restrict__ bfc,
                          float* __restrict__ out) {
    int b = threadIdx.x;
    if (b < N_GRAPHS) {
        float inv = 1.0f / fmaxf(gcnt[b], 1.0f);
        float acc = bfc[0];
#pragma unroll
        for (int k = 0; k < 32; k++)
            acc += (float)gsumi[b * 32 + k] * POOL_INV * inv * Wfc[k];
        out[b] = 1.0f / (1.0f + expf(-acc));
    }
}

// ---- launch ----
extern "C" void kernel_launch(void* const* d_in, const int* in_sizes, int n_in,
                              void* d_out, int out_size, void* d_ws, size_t ws_size,
                              hipStream_t stream) {
    const float* x    = (const float*)d_in[0];
    const int*   ei   = (const int*)d_in[1];
    const int*   batch= (const int*)d_in[2];
    const float* W1   = (const float*)d_in[3];
    const float* b1   = (const float*)d_in[4];
    const float* W2   = (const float*)d_in[5];
    const float* b2   = (const float*)d_in[6];
    const float* Wfc  = (const float*)d_in[7];
    const float* bfc  = (const float*)d_in[8];
    float* out = (float*)d_out;

    const int* srcIdx = ei;
    const int* dstIdx = ei + N_EDGES;

    char* w = (char*)d_ws;
    unsigned int* totals  = (unsigned int*)w; w += ((NBUCK + 64) & ~63) * 4;
    unsigned int* base    = (unsigned int*)w; w += ((NBUCK + 1 + 63) & ~63) * 4;
    unsigned int* gcur    = (unsigned int*)w; w += ((NBUCK + 64) & ~63) * 4;
    unsigned int* deg     = (unsigned int*)w; w += (size_t)((N_NODES + 63) & ~63) * 4;
    unsigned int* packed  = (unsigned int*)w; w += (size_t)N_EDGES * 4;
    unsigned int* packed2 = (unsigned int*)w; w += (size_t)(N_EDGES + 64) * 4;
    unsigned int* rowstart= (unsigned int*)w; w += (size_t)(NBUCK * BW + 64) * 4;
    float* dinv = (float*)w;                  w += (size_t)N_NODES * 4;
    float* sbuf = (float*)w;                  w += (size_t)N_NODES * 4;
    float2* ac  = (float2*)w;                 w += (size_t)(N_NODES + 8) * 8;
    int* gsumi  = (int*)w;                    w += (size_t)N_GRAPHS * 32 * 4;
    float* gcnt = (float*)w;                  w += (size_t)N_GRAPHS * 4;

    hipMemsetAsync(deg, 0, (size_t)N_NODES * 4, stream);
    hipMemsetAsync(gcur, 0, (size_t)NBUCK * 4, stream);
    hipMemsetAsync(gsumi, 0, (size_t)N_GRAPHS * 32 * 4, stream);

    k_deg  <<<2048, 256, 0, stream>>>(dstIdx, deg);
    k_base <<<NBUCK, 128, 0, stream>>>(deg, x, dinv, sbuf, ac, totals);
    k_scanb<<<1, 1024, 0, stream>>>(totals, base);
    k_part <<<NCHUNK, 512, 0, stream>>>(srcIdx, dstIdx, base, gcur, packed);
    k_sort <<<NBUCK, 512, 0, stream>>>(base, packed, packed2, rowstart, dinv, sbuf, ac);
    k_gcnt <<<1, 128, 0, stream>>>(batch, gcnt);
    k_l2   <<<(N_NODES + 4 * NPW - 1) / (4 * NPW), 256, 0, stream>>>(rowstart, packed2, ac, W1, b1, W2, b2, batch, gsumi);
    k_readout<<<1, 64, 0, stream>>>(gsumi, gcnt, Wfc, bfc, out);
}

// Round 11
// 229.007 us; speedup vs baseline: 1.5752x; 1.5752x over previous
//
#include <hip/hip_runtime.h>
#include <math.h>

#define N_NODES 100000
#define N_EDGES 3200000
#define N_GRAPHS 64
#define BW 512                               // nodes per bucket (r11: 128->512, quadruples k_part run length)
#define LSH 9
#define LMASK 511u
#define NBUCK ((N_NODES + BW - 1) / BW)      // 196
#define CHUNK_E 8192
#define NCHUNK ((N_EDGES + CHUNK_E - 1) / CHUNK_E)  // 391
#define POOL_SCALE 1024.0f
#define POOL_INV (1.0f / 1024.0f)
#define SENT ((unsigned int)N_NODES << LSH)  // sentinel edge -> ac[N_NODES] == (0,0); fits 32b (51.2M)

// ---- pass A: per-chunk bucket histogram (int LDS atomics — native) ----
__global__ void k_count(const int* __restrict__ dst, unsigned int* __restrict__ counts,
                        unsigned int* __restrict__ totals) {
    __shared__ unsigned int h[NBUCK];
    for (int i = threadIdx.x; i < NBUCK; i += blockDim.x) h[i] = 0u;
    __syncthreads();
    int e0 = blockIdx.x * CHUNK_E;
    int e1 = min(e0 + CHUNK_E, N_EDGES);
    for (int e = e0 + threadIdx.x; e < e1; e += blockDim.x)
        atomicAdd(&h[dst[e] >> LSH], 1u);
    __syncthreads();
    for (int i = threadIdx.x; i < NBUCK; i += blockDim.x) {
        counts[(size_t)blockIdx.x * NBUCK + i] = h[i];
        if (h[i]) atomicAdd(&totals[i], h[i]);
    }
}

// ---- pass B+C fused: per-bucket base from totals-scan, then chunk scan ----
__global__ void k_scanc(unsigned int* __restrict__ counts, const unsigned int* __restrict__ totals,
                        unsigned int* __restrict__ base) {
    __shared__ unsigned int sd[1024];
    __shared__ unsigned int sbase;
    int bk = blockIdx.x;
    int t = threadIdx.x;
    // phase 1: inclusive scan of totals -> this bucket's exclusive base
    unsigned int tv = (t < NBUCK) ? totals[t] : 0u;
    sd[t] = tv;
    __syncthreads();
    for (int o = 1; o < 1024; o <<= 1) {
        unsigned int x = (t >= o) ? sd[t - o] : 0u;
        __syncthreads();
        sd[t] += x;
        __syncthreads();
    }
    if (t == bk) {
        sbase = sd[t] - tv;
        base[bk] = sd[t] - tv;
        if (bk == 0) base[NBUCK] = N_EDGES;
    }
    __syncthreads();
    // phase 2: per-bucket scan over chunks -> counts = start[chunk][bucket]
    unsigned int v = (t < NCHUNK) ? counts[(size_t)t * NBUCK + bk] : 0u;
    sd[t] = v;
    __syncthreads();
    for (int o = 1; o < 1024; o <<= 1) {
        unsigned int x = (t >= o) ? sd[t - o] : 0u;
        __syncthreads();
        sd[t] += x;
        __syncthreads();
    }
    if (t < NCHUNK) counts[(size_t)t * NBUCK + bk] = sbase + sd[t] - v;
}

// ---- pass D: place edges into buckets (int LDS cursors — native) ----
// Bucket-confined writes keep the active write set at ~196 moving pointers.
// Round-2/10 post-mortems: per-NODE global cursors / random global atomics
// thrash the coherence point (100-200MB WRITE_SIZE). Do not de-bucket this.
__global__ void k_part(const int* __restrict__ src, const int* __restrict__ dst,
                       const unsigned int* __restrict__ counts, unsigned int* __restrict__ packed) {
    __shared__ unsigned int sstart[NBUCK];
    __shared__ unsigned int lcur[NBUCK];
    for (int i = threadIdx.x; i < NBUCK; i += blockDim.x) {
        sstart[i] = counts[(size_t)blockIdx.x * NBUCK + i];
        lcur[i] = 0u;
    }
    __syncthreads();
    int e0 = blockIdx.x * CHUNK_E;
    int e1 = min(e0 + CHUNK_E, N_EDGES);
    for (int e = e0 + threadIdx.x; e < e1; e += blockDim.x) {
        int d = dst[e];
        int bk = d >> LSH;
        unsigned int pos = sstart[bk] + atomicAdd(&lcur[bk], 1u);
        packed[pos] = ((unsigned int)src[e] << LSH) | ((unsigned int)d & LMASK);
    }
}

// ---- pass E: per-bucket exact dst sort -> packed2 + rowstart (all int) ----
// BW=512 counters, 1024 threads, 196 blocks (3136 waves ~ 3/SIMD).
__global__ void k_sort(const unsigned int* __restrict__ base, const unsigned int* __restrict__ packed,
                       unsigned int* __restrict__ packed2, unsigned int* __restrict__ rowstart) {
    __shared__ unsigned int hist[BW];
    __shared__ unsigned int scan[BW];
    __shared__ unsigned int cur[BW];
    int b = blockIdx.x;
    unsigned int e0 = base[b], e1 = base[b + 1];
    if (threadIdx.x < BW) hist[threadIdx.x] = 0u;
    __syncthreads();
    for (unsigned int e = e0 + threadIdx.x; e < e1; e += blockDim.x)
        atomicAdd(&hist[packed[e] & LMASK], 1u);
    __syncthreads();
    if (threadIdx.x < BW) scan[threadIdx.x] = hist[threadIdx.x];
    __syncthreads();
    for (int o = 1; o < BW; o <<= 1) {
        unsigned int v = 0u;
        if (threadIdx.x < BW && threadIdx.x >= (unsigned)o) v = scan[threadIdx.x - o];
        __syncthreads();
        if (threadIdx.x < BW && threadIdx.x >= (unsigned)o) scan[threadIdx.x] += v;
        __syncthreads();
    }
    if (threadIdx.x < BW) {
        unsigned int excl = scan[threadIdx.x] - hist[threadIdx.x];
        cur[threadIdx.x] = excl;
        rowstart[b * BW + threadIdx.x] = e0 + excl;
    }
    __syncthreads();
    for (unsigned int e = e0 + threadIdx.x; e < e1; e += blockDim.x) {
        unsigned int p = packed[e];
        unsigned int pos = e0 + atomicAdd(&cur[p & LMASK], 1u);
        packed2[pos] = p;
    }
}

// ---- dinv/s from rowstart diffs (no atomics); also zero the ac sentinel slot ----
__global__ void k_dinv(const unsigned int* __restrict__ rowstart, const float* __restrict__ x,
                       float* __restrict__ dinv, float* __restrict__ s, float2* __restrict__ ac) {
    int n = blockIdx.x * blockDim.x + threadIdx.x;
    if (n == 0) ac[N_NODES] = make_float2(0.0f, 0.0f);   // sentinel for padded edge slots in k_l2
    if (n < N_NODES) {
        unsigned int deg = rowstart[n + 1] - rowstart[n];
        float di = 1.0f / sqrtf((float)(deg + 1u));  // +1 self-loop
        dinv[n] = di;
        s[n] = x[n] * di;
    }
}

// ---- graph node counts via binary search (no atomics) ----
__global__ void k_gcnt(const int* __restrict__ batch, float* __restrict__ gcnt) {
    __shared__ int lb[N_GRAPHS + 1];
    int b = threadIdx.x;
    if (b <= N_GRAPHS) {
        int lo = 0, hi = N_NODES;
        while (lo < hi) {
            int mid = (lo + hi) >> 1;
            if (batch[mid] < b) lo = mid + 1; else hi = mid;
        }
        lb[b] = lo;
    }
    __syncthreads();
    if (b < N_GRAPHS) gcnt[b] = (float)(lb[b + 1] - lb[b]);
}

// ---- layer 1: lane-per-edge gather + shfl reduce (16 nodes/block -> 6250 blocks) ----
// ROUND-5 FORM: ac[n] = (di, di*di*(sum + s[n])).
#define NB1 16
__global__ void k_l1(const unsigned int* __restrict__ rowstart, const unsigned int* __restrict__ packed2,
                     const float* __restrict__ dinv, const float* __restrict__ s,
                     float2* __restrict__ ac) {
    int g = threadIdx.x >> 5, k = threadIdx.x & 31;
    int b = blockIdx.x;
    for (int d = g; d < NB1; d += 8) {
        int n = b * NB1 + d;
        if (n >= N_NODES) break;
        unsigned int rs = rowstart[n], re = rowstart[n + 1];
        float sum = 0.0f;
        for (unsigned int e = rs + k; e < re; e += 32)
            sum += s[packed2[e] >> LSH];
        sum += __shfl_xor(sum, 1);
        sum += __shfl_xor(sum, 2);
        sum += __shfl_xor(sum, 4);
        sum += __shfl_xor(sum, 8);
        sum += __shfl_xor(sum, 16);   // masks <32: stays within the 32-lane half
        if (k == 0) {
            float di = dinv[n];
            ac[n] = make_float2(di, di * di * (sum + s[n]));
        }
    }
}

// ---- layer 2: one 64-lane wave per node, lane j = column j ----
// ROUND-5 KERNEL VERBATIM — proven 36 VGPR, zero scratch, 54-56 µs, FETCH 10 MB.
// DO NOT EDIT THIS KERNEL'S BODY: rounds 6/7/8 each made small changes (packed
// math; prefetch+4 accumulators; even a 2-accumulator algebra tweak) and ALL
// tipped the register allocator into demoting w2c[32] to scratch — 100-310 MB
// of HBM scratch traffic, 2-3x kernel slowdown, and graph-replay-wide damage.
// The codegen sits exactly on a register-bucket boundary.
// (r11: only the LSH shift constant changed — no live-state change.)
#define NPW 8

#define EDGE_PAIR(P) { \
    float4 q_ = Epair4[(P)]; \
    H += fmaxf(fmaf(q_.y, w1j, q_.x * b1j), 0.0f); \
    H += fmaxf(fmaf(q_.w, w1j, q_.z * b1j), 0.0f); }

#define BLOCK16(P0) { \
    EDGE_PAIR((P0) + 0) EDGE_PAIR((P0) + 1) EDGE_PAIR((P0) + 2) EDGE_PAIR((P0) + 3) \
    EDGE_PAIR((P0) + 4) EDGE_PAIR((P0) + 5) EDGE_PAIR((P0) + 6) EDGE_PAIR((P0) + 7) }

__global__ __launch_bounds__(256, 6)
void k_l2(const unsigned int* __restrict__ rowstart, const unsigned int* __restrict__ packed2,
          const float2* __restrict__ ac,
          const float* __restrict__ W1, const float* __restrict__ b1,
          const float* __restrict__ W2, const float* __restrict__ b2,
          const int* __restrict__ batch, int* __restrict__ gsumi) {
    __shared__ float Hrow[4][64];    // one 64-float row per wave; wave-private
    __shared__ float4 Ebuf[4][32];   // 64 (ax,ay) pairs per wave, read as float4 (2 edges/read)
    const int lane = threadIdx.x & 63;
    const int wv   = threadIdx.x >> 6;
    const int k    = lane & 31;     // output column for matvec/pool
    const int jh   = lane >> 5;     // which half of the 64-wide hidden dim this lane reduces
    const int j0   = jh * 32;

    const float w1j = W1[lane];
    const float b1j = b1[lane];
    const float b2k = b2[k];
    float w2c[32];
#pragma unroll
    for (int j = 0; j < 32; j++) w2c[j] = W2[(j0 + j) * 32 + k];

    float4* Epair4 = &Ebuf[wv][0];                 // wave-uniform base
    float2* Ewr    = (float2*)&Ebuf[wv][0];        // per-lane write slot

    int n0 = (blockIdx.x * 4 + wv) * NPW;
    float racc = 0.0f;
    int curg = -1;
    for (int i = 0; i < NPW; i++) {
        int n = n0 + i;
        if (n >= N_NODES) break;
        unsigned int rs = rowstart[n], re = rowstart[n + 1];
        float2 acn = ac[n];
        // self-loop contribution
        float H = fmaxf(fmaf(acn.y, w1j, acn.x * b1j), 0.0f);
        unsigned int e0 = rs;
        // full 64-slot batches (deg >= 64, rare at Poisson(32))
        while (e0 + 64u <= re) {
            unsigned int p = packed2[e0 + lane];     // all lanes valid
            Ewr[lane] = ac[p >> LSH];                // gather -> wave-private LDS (ds_write_b64)
            BLOCK16(0) BLOCK16(8) BLOCK16(16) BLOCK16(24)
            e0 += 64u;
        }
        unsigned int rem = re - e0;                  // 0..63
        if (rem) {
            unsigned int idx = e0 + lane;
            unsigned int p = SENT;                   // sentinel -> ac[N_NODES] == (0,0)
            if (idx < re) p = packed2[idx];          // exec-masked load, no OOB
            Ewr[lane] = ac[p >> LSH];
            switch ((rem + 15u) >> 4) {              // 1..4 blocks of 16 slots (8 pairs)
                case 4: BLOCK16(24); [[fallthrough]];
                case 3: BLOCK16(16); [[fallthrough]];
                case 2: BLOCK16(8);  [[fallthrough]];
                case 1: BLOCK16(0);
            }
        }
        // matvec: out_k = relu(dinv_n * (H . W2[:,k]) + b2[k])
        Hrow[wv][lane] = H;     // same-wave ds ordering: visible to this wave without barrier
        float accv = 0.0f;
#pragma unroll
        for (int jj = 0; jj < 8; jj++) {
            float4 hv = *(const float4*)&Hrow[wv][j0 + 4 * jj];
            accv += hv.x * w2c[4 * jj + 0] + hv.y * w2c[4 * jj + 1]
                  + hv.z * w2c[4 * jj + 2] + hv.w * w2c[4 * jj + 3];
        }
        accv += __shfl_xor(accv, 32);   // combine half-partials (width 64)
        float v = fmaxf(fmaf(acn.x, accv, b2k), 0.0f);
        int gb = batch[n];               // wave-uniform scalar load
        if (gb != curg) {
            if (curg >= 0 && jh == 0)
                atomicAdd(&gsumi[curg * 32 + k], __float2int_rn(racc * POOL_SCALE));
            racc = 0.0f; curg = gb;
        }
        racc += v;
    }
    if (curg >= 0 && jh == 0)
        atomicAdd(&gsumi[curg * 32 + k], __float2int_rn(racc * POOL_SCALE));
}

// ---- readout ----
__global__ void k_readout(const int* __restrict__ gsumi, const float* __restrict__ gcnt,
                          const float* __restrict__ Wfc, const float* __restrict__ bfc,
                          float* __restrict__ out) {
    int b = threadIdx.x;
    if (b < N_GRAPHS) {
        float inv = 1.0f / fmaxf(gcnt[b], 1.0f);
        float acc = bfc[0];
#pragma unroll
        for (int k = 0; k < 32; k++)
            acc += (float)gsumi[b * 32 + k] * POOL_INV * inv * Wfc[k];
        out[b] = 1.0f / (1.0f + expf(-acc));
    }
}

// ---- launch ----
extern "C" void kernel_launch(void* const* d_in, const int* in_sizes, int n_in,
                              void* d_out, int out_size, void* d_ws, size_t ws_size,
                              hipStream_t stream) {
    const float* x    = (const float*)d_in[0];
    const int*   ei   = (const int*)d_in[1];
    const int*   batch= (const int*)d_in[2];
    const float* W1   = (const float*)d_in[3];
    const float* b1   = (const float*)d_in[4];
    const float* W2   = (const float*)d_in[5];
    const float* b2   = (const float*)d_in[6];
    const float* Wfc  = (const float*)d_in[7];
    const float* bfc  = (const float*)d_in[8];
    float* out = (float*)d_out;

    const int* srcIdx = ei;
    const int* dstIdx = ei + N_EDGES;

    char* w = (char*)d_ws;
    unsigned int* totals  = (unsigned int*)w; w += ((NBUCK + 64) & ~63) * 4;
    unsigned int* base    = (unsigned int*)w; w += ((NBUCK + 1 + 63) & ~63) * 4;
    unsigned int* packed  = (unsigned int*)w; w += (size_t)N_EDGES * 4;
    unsigned int* packed2 = (unsigned int*)w; w += (size_t)(N_EDGES + 64) * 4;
    unsigned int* rowstart= (unsigned int*)w; w += (size_t)(NBUCK * BW + 64) * 4;
    float* dinv = (float*)w;                  w += (size_t)N_NODES * 4;
    float* sbuf = (float*)w;                  w += (size_t)N_NODES * 4;
    float2* ac  = (float2*)w;                 w += (size_t)(N_NODES + 8) * 8;
    int* gsumi  = (int*)w;                    w += (size_t)N_GRAPHS * 32 * 4;
    float* gcnt = (float*)w;                  w += (size_t)N_GRAPHS * 4;
    // counts (NCHUNK x NBUCK = 391*196*4 = 306KB) aliased onto packed2:
    // counts is dead before k_sort writes packed2 (k_count->scanc->k_part read it first).
    unsigned int* counts  = packed2;

    hipMemsetAsync(totals, 0, (size_t)NBUCK * 4, stream);
    hipMemsetAsync(gsumi, 0, (size_t)N_GRAPHS * 32 * 4, stream);

    k_count<<<NCHUNK, 512, 0, stream>>>(dstIdx, counts, totals);
    k_scanc<<<NBUCK, 1024, 0, stream>>>(counts, totals, base);
    k_part <<<NCHUNK, 512, 0, stream>>>(srcIdx, dstIdx, counts, packed);
    k_sort <<<NBUCK, 1024, 0, stream>>>(base, packed, packed2, rowstart);
    k_dinv <<<(N_NODES + 255) / 256, 256, 0, stream>>>(rowstart, x, dinv, sbuf, ac);
    k_gcnt <<<1, 128, 0, stream>>>(batch, gcnt);
    k_l1   <<<(N_NODES + NB1 - 1) / NB1, 256, 0, stream>>>(rowstart, packed2, dinv, sbuf, ac);
    k_l2   <<<(N_NODES + 4 * NPW - 1) / (4 * NPW), 256, 0, stream>>>(rowstart, packed2, ac, W1, b1, W2, b2, batch, gsumi);
    k_readout<<<1, 64, 0, stream>>>(gsumi, gcnt, Wfc, bfc, out);
}

// Round 12
// 220.354 us; speedup vs baseline: 1.6370x; 1.0393x over previous
//
#include <hip/hip_runtime.h>
#include <math.h>

#define N_NODES 100000
#define N_EDGES 3200000
#define N_GRAPHS 64
#define BW 512                               // nodes per bucket
#define LSH 9
#define LMASK 511u
#define NBUCK ((N_NODES + BW - 1) / BW)      // 196
#define CHUNK_E 8192
#define NCHUNK ((N_EDGES + CHUNK_E - 1) / CHUNK_E)  // 391
#define POOL_SCALE 1024.0f
#define POOL_INV (1.0f / 1024.0f)
#define SENT ((unsigned int)N_NODES << LSH)  // sentinel edge -> ac[N_NODES] == (0,0)

// ---- pass A: per-chunk bucket histogram (int LDS atomics — native) ----
__global__ void k_count(const int* __restrict__ dst, unsigned int* __restrict__ counts,
                        unsigned int* __restrict__ totals) {
    __shared__ unsigned int h[NBUCK];
    for (int i = threadIdx.x; i < NBUCK; i += blockDim.x) h[i] = 0u;
    __syncthreads();
    int e0 = blockIdx.x * CHUNK_E;
    int e1 = min(e0 + CHUNK_E, N_EDGES);
    for (int e = e0 + threadIdx.x; e < e1; e += blockDim.x)
        atomicAdd(&h[dst[e] >> LSH], 1u);
    __syncthreads();
    for (int i = threadIdx.x; i < NBUCK; i += blockDim.x) {
        counts[(size_t)blockIdx.x * NBUCK + i] = h[i];
        if (h[i]) atomicAdd(&totals[i], h[i]);
    }
}

// ---- pass B+C fused: per-bucket base from totals-scan, then chunk scan ----
__global__ void k_scanc(unsigned int* __restrict__ counts, const unsigned int* __restrict__ totals,
                        unsigned int* __restrict__ base) {
    __shared__ unsigned int sd[1024];
    __shared__ unsigned int sbase;
    int bk = blockIdx.x;
    int t = threadIdx.x;
    // phase 1: inclusive scan of totals -> this bucket's exclusive base
    unsigned int tv = (t < NBUCK) ? totals[t] : 0u;
    sd[t] = tv;
    __syncthreads();
    for (int o = 1; o < 1024; o <<= 1) {
        unsigned int x = (t >= o) ? sd[t - o] : 0u;
        __syncthreads();
        sd[t] += x;
        __syncthreads();
    }
    if (t == bk) {
        sbase = sd[t] - tv;
        base[bk] = sd[t] - tv;
        if (bk == 0) base[NBUCK] = N_EDGES;
    }
    __syncthreads();
    // phase 2: per-bucket scan over chunks -> counts = start[chunk][bucket]
    unsigned int v = (t < NCHUNK) ? counts[(size_t)t * NBUCK + bk] : 0u;
    sd[t] = v;
    __syncthreads();
    for (int o = 1; o < 1024; o <<= 1) {
        unsigned int x = (t >= o) ? sd[t - o] : 0u;
        __syncthreads();
        sd[t] += x;
        __syncthreads();
    }
    if (t < NCHUNK) counts[(size_t)t * NBUCK + bk] = sbase + sd[t] - v;
}

// ---- pass D: place edges into buckets (int LDS cursors — native) ----
// Bucket-confined writes keep the active write set at ~196 moving pointers.
// Round-2/10 post-mortems: per-NODE global cursors / random global atomics
// thrash the coherence point (100-200MB WRITE_SIZE). Do not de-bucket this.
__global__ void k_part(const int* __restrict__ src, const int* __restrict__ dst,
                       const unsigned int* __restrict__ counts, unsigned int* __restrict__ packed) {
    __shared__ unsigned int sstart[NBUCK];
    __shared__ unsigned int lcur[NBUCK];
    for (int i = threadIdx.x; i < NBUCK; i += blockDim.x) {
        sstart[i] = counts[(size_t)blockIdx.x * NBUCK + i];
        lcur[i] = 0u;
    }
    __syncthreads();
    int e0 = blockIdx.x * CHUNK_E;
    int e1 = min(e0 + CHUNK_E, N_EDGES);
    for (int e = e0 + threadIdx.x; e < e1; e += blockDim.x) {
        int d = dst[e];
        int bk = d >> LSH;
        unsigned int pos = sstart[bk] + atomicAdd(&lcur[bk], 1u);
        packed[pos] = ((unsigned int)src[e] << LSH) | ((unsigned int)d & LMASK);
    }
}

// ---- pass E1: per-bucket histogram + scan -> rowstart, dinv, s (absorbs k_dinv) ----
// hist[t] IS node (b*BW+t)'s degree — dinv/s computed here, before any scatter.
__global__ void k_sorta(const unsigned int* __restrict__ base, const unsigned int* __restrict__ packed,
                        unsigned int* __restrict__ rowstart, const float* __restrict__ x,
                        float* __restrict__ dinv, float* __restrict__ s, float2* __restrict__ ac) {
    __shared__ unsigned int hist[BW];
    __shared__ unsigned int scan[BW];
    int b = blockIdx.x;
    unsigned int e0 = base[b], e1 = base[b + 1];
    if (threadIdx.x < BW) hist[threadIdx.x] = 0u;
    if (b == 0 && threadIdx.x == 0) ac[N_NODES] = make_float2(0.0f, 0.0f);  // k_l2 sentinel
    __syncthreads();
    for (unsigned int e = e0 + threadIdx.x; e < e1; e += blockDim.x)
        atomicAdd(&hist[packed[e] & LMASK], 1u);
    __syncthreads();
    if (threadIdx.x < BW) scan[threadIdx.x] = hist[threadIdx.x];
    __syncthreads();
    for (int o = 1; o < BW; o <<= 1) {
        unsigned int v = 0u;
        if (threadIdx.x < BW && threadIdx.x >= (unsigned)o) v = scan[threadIdx.x - o];
        __syncthreads();
        if (threadIdx.x < BW && threadIdx.x >= (unsigned)o) scan[threadIdx.x] += v;
        __syncthreads();
    }
    if (threadIdx.x < BW) {
        unsigned int deg = hist[threadIdx.x];
        rowstart[b * BW + threadIdx.x] = e0 + scan[threadIdx.x] - deg;
        int n = b * BW + threadIdx.x;
        if (n < N_NODES) {
            float di = 1.0f / sqrtf((float)(deg + 1u));  // +1 self-loop
            dinv[n] = di;
            s[n] = x[n] * di;
        }
    }
}

// ---- pass E2: scatter -> packed2, FUSED with layer 1 (absorbs k_l1) ----
// Cursors rebuilt from rowstart (512 loads). Per edge, fsum[d] += s[src]
// (native ds_add_f32) — deletes k_l1's separate 12.8MB packed2 re-read.
// Accumulation order is LDS-atomic-nondeterministic: same class as the edge
// order (already atomic); the int-quantized pooling absorbs it.
__global__ void k_sortb(const unsigned int* __restrict__ base, const unsigned int* __restrict__ packed,
                        const unsigned int* __restrict__ rowstart,
                        unsigned int* __restrict__ packed2,
                        const float* __restrict__ dinv, const float* __restrict__ s,
                        float2* __restrict__ ac) {
    __shared__ unsigned int cur[BW];
    __shared__ float fsum[BW];
    int b = blockIdx.x;
    unsigned int e0 = base[b], e1 = base[b + 1];
    if (threadIdx.x < BW) {
        cur[threadIdx.x] = rowstart[b * BW + threadIdx.x] - e0;
        fsum[threadIdx.x] = 0.0f;
    }
    __syncthreads();
    for (unsigned int e = e0 + threadIdx.x; e < e1; e += blockDim.x) {
        unsigned int p = packed[e];
        unsigned int d = p & LMASK;
        unsigned int pos = e0 + atomicAdd(&cur[d], 1u);
        packed2[pos] = p;
        atomicAdd(&fsum[d], s[p >> LSH]);   // layer-1 neighbor sum (ds_add_f32, L2-resident gather)
    }
    __syncthreads();
    if (threadIdx.x < BW) {
        int n = b * BW + threadIdx.x;
        if (n < N_NODES) {
            float di = dinv[n];
            ac[n] = make_float2(di, di * di * (fsum[threadIdx.x] + s[n]));
        }
    }
}

// ---- graph node counts via binary search (no atomics) ----
__global__ void k_gcnt(const int* __restrict__ batch, float* __restrict__ gcnt) {
    __shared__ int lb[N_GRAPHS + 1];
    int b = threadIdx.x;
    if (b <= N_GRAPHS) {
        int lo = 0, hi = N_NODES;
        while (lo < hi) {
            int mid = (lo + hi) >> 1;
            if (batch[mid] < b) lo = mid + 1; else hi = mid;
        }
        lb[b] = lo;
    }
    __syncthreads();
    if (b < N_GRAPHS) gcnt[b] = (float)(lb[b + 1] - lb[b]);
}

// ---- layer 2: one 64-lane wave per node, lane j = column j ----
// ROUND-5 KERNEL VERBATIM — proven 36 VGPR, zero scratch, 54-56 µs, FETCH 10 MB.
// DO NOT EDIT THIS KERNEL'S BODY: rounds 6/7/8 each made small changes (packed
// math; prefetch+4 accumulators; even a 2-accumulator algebra tweak) and ALL
// tipped the register allocator into demoting w2c[32] to scratch — 100-310 MB
// of HBM scratch traffic, 2-3x kernel slowdown, and graph-replay-wide damage.
// The codegen sits exactly on a register-bucket boundary.
#define NPW 8

#define EDGE_PAIR(P) { \
    float4 q_ = Epair4[(P)]; \
    H += fmaxf(fmaf(q_.y, w1j, q_.x * b1j), 0.0f); \
    H += fmaxf(fmaf(q_.w, w1j, q_.z * b1j), 0.0f); }

#define BLOCK16(P0) { \
    EDGE_PAIR((P0) + 0) EDGE_PAIR((P0) + 1) EDGE_PAIR((P0) + 2) EDGE_PAIR((P0) + 3) \
    EDGE_PAIR((P0) + 4) EDGE_PAIR((P0) + 5) EDGE_PAIR((P0) + 6) EDGE_PAIR((P0) + 7) }

__global__ __launch_bounds__(256, 6)
void k_l2(const unsigned int* __restrict__ rowstart, const unsigned int* __restrict__ packed2,
          const float2* __restrict__ ac,
          const float* __restrict__ W1, const float* __restrict__ b1,
          const float* __restrict__ W2, const float* __restrict__ b2,
          const int* __restrict__ batch, int* __restrict__ gsumi) {
    __shared__ float Hrow[4][64];    // one 64-float row per wave; wave-private
    __shared__ float4 Ebuf[4][32];   // 64 (ax,ay) pairs per wave, read as float4 (2 edges/read)
    const int lane = threadIdx.x & 63;
    const int wv   = threadIdx.x >> 6;
    const int k    = lane & 31;     // output column for matvec/pool
    const int jh   = lane >> 5;     // which half of the 64-wide hidden dim this lane reduces
    const int j0   = jh * 32;

    const float w1j = W1[lane];
    const float b1j = b1[lane];
    const float b2k = b2[k];
    float w2c[32];
#pragma unroll
    for (int j = 0; j < 32; j++) w2c[j] = W2[(j0 + j) * 32 + k];

    float4* Epair4 = &Ebuf[wv][0];                 // wave-uniform base
    float2* Ewr    = (float2*)&Ebuf[wv][0];        // per-lane write slot

    int n0 = (blockIdx.x * 4 + wv) * NPW;
    float racc = 0.0f;
    int curg = -1;
    for (int i = 0; i < NPW; i++) {
        int n = n0 + i;
        if (n >= N_NODES) break;
        unsigned int rs = rowstart[n], re = rowstart[n + 1];
        float2 acn = ac[n];
        // self-loop contribution
        float H = fmaxf(fmaf(acn.y, w1j, acn.x * b1j), 0.0f);
        unsigned int e0 = rs;
        // full 64-slot batches (deg >= 64, rare at Poisson(32))
        while (e0 + 64u <= re) {
            unsigned int p = packed2[e0 + lane];     // all lanes valid
            Ewr[lane] = ac[p >> LSH];                // gather -> wave-private LDS (ds_write_b64)
            BLOCK16(0) BLOCK16(8) BLOCK16(16) BLOCK16(24)
            e0 += 64u;
        }
        unsigned int rem = re - e0;                  // 0..63
        if (rem) {
            unsigned int idx = e0 + lane;
            unsigned int p = SENT;                   // sentinel -> ac[N_NODES] == (0,0)
            if (idx < re) p = packed2[idx];          // exec-masked load, no OOB
            Ewr[lane] = ac[p >> LSH];
            switch ((rem + 15u) >> 4) {              // 1..4 blocks of 16 slots (8 pairs)
                case 4: BLOCK16(24); [[fallthrough]];
                case 3: BLOCK16(16); [[fallthrough]];
                case 2: BLOCK16(8);  [[fallthrough]];
                case 1: BLOCK16(0);
            }
        }
        // matvec: out_k = relu(dinv_n * (H . W2[:,k]) + b2[k])
        Hrow[wv][lane] = H;     // same-wave ds ordering: visible to this wave without barrier
        float accv = 0.0f;
#pragma unroll
        for (int jj = 0; jj < 8; jj++) {
            float4 hv = *(const float4*)&Hrow[wv][j0 + 4 * jj];
            accv += hv.x * w2c[4 * jj + 0] + hv.y * w2c[4 * jj + 1]
                  + hv.z * w2c[4 * jj + 2] + hv.w * w2c[4 * jj + 3];
        }
        accv += __shfl_xor(accv, 32);   // combine half-partials (width 64)
        float v = fmaxf(fmaf(acn.x, accv, b2k), 0.0f);
        int gb = batch[n];               // wave-uniform scalar load
        if (gb != curg) {
            if (curg >= 0 && jh == 0)
                atomicAdd(&gsumi[curg * 32 + k], __float2int_rn(racc * POOL_SCALE));
            racc = 0.0f; curg = gb;
        }
        racc += v;
    }
    if (curg >= 0 && jh == 0)
        atomicAdd(&gsumi[curg * 32 + k], __float2int_rn(racc * POOL_SCALE));
}

// ---- readout ----
__global__ void k_readout(const int* __restrict__ gsumi, const float* __restrict__ gcnt,
                          const float* __restrict__ Wfc, const float* __restrict__ bfc,
                          float* __restrict__ out) {
    int b = threadIdx.x;
    if (b < N_GRAPHS) {
        float inv = 1.0f / fmaxf(gcnt[b], 1.0f);
        float acc = bfc[0];
#pragma unroll
        for (int k = 0; k < 32; k++)
            acc += (float)gsumi[b * 32 + k] * POOL_INV * inv * Wfc[k];
        out[b] = 1.0f / (1.0f + expf(-acc));
    }
}

// ---- launch ----
extern "C" void kernel_launch(void* const* d_in, const int* in_sizes, int n_in,
                              void* d_out, int out_size, void* d_ws, size_t ws_size,
                              hipStream_t stream) {
    const float* x    = (const float*)d_in[0];
    const int*   ei   = (const int*)d_in[1];
    const int*   batch= (const int*)d_in[2];
    const float* W1   = (const float*)d_in[3];
    const float* b1   = (const float*)d_in[4];
    const float* W2   = (const float*)d_in[5];
    const float* b2   = (const float*)d_in[6];
    const float* Wfc  = (const float*)d_in[7];
    const float* bfc  = (const float*)d_in[8];
    float* out = (float*)d_out;

    const int* srcIdx = ei;
    const int* dstIdx = ei + N_EDGES;

    char* w = (char*)d_ws;
    unsigned int* totals  = (unsigned int*)w; w += ((NBUCK + 64) & ~63) * 4;
    unsigned int* base    = (unsigned int*)w; w += ((NBUCK + 1 + 63) & ~63) * 4;
    unsigned int* packed  = (unsigned int*)w; w += (size_t)N_EDGES * 4;
    unsigned int* packed2 = (unsigned int*)w; w += (size_t)(N_EDGES + 64) * 4;
    unsigned int* rowstart= (unsigned int*)w; w += (size_t)(NBUCK * BW + 64) * 4;
    float* dinv = (float*)w;                  w += (size_t)N_NODES * 4;
    float* sbuf = (float*)w;                  w += (size_t)N_NODES * 4;
    float2* ac  = (float2*)w;                 w += (size_t)(N_NODES + 8) * 8;
    int* gsumi  = (int*)w;                    w += (size_t)N_GRAPHS * 32 * 4;
    float* gcnt = (float*)w;                  w += (size_t)N_GRAPHS * 4;
    // counts (NCHUNK x NBUCK = 391*196*4 = 306KB) aliased onto packed2:
    // counts is dead before k_sortb writes packed2 (k_count->scanc->k_part read it first).
    unsigned int* counts  = packed2;

    hipMemsetAsync(totals, 0, (size_t)NBUCK * 4, stream);
    hipMemsetAsync(gsumi, 0, (size_t)N_GRAPHS * 32 * 4, stream);

    k_count<<<NCHUNK, 512, 0, stream>>>(dstIdx, counts, totals);
    k_scanc<<<NBUCK, 1024, 0, stream>>>(counts, totals, base);
    k_part <<<NCHUNK, 512, 0, stream>>>(srcIdx, dstIdx, counts, packed);
    k_sorta<<<NBUCK, 1024, 0, stream>>>(base, packed, rowstart, x, dinv, sbuf, ac);
    k_sortb<<<NBUCK, 1024, 0, stream>>>(base, packed, rowstart, packed2, dinv, sbuf, ac);
    k_gcnt <<<1, 128, 0, stream>>>(batch, gcnt);
    k_l2   <<<(N_NODES + 4 * NPW - 1) / (4 * NPW), 256, 0, stream>>>(rowstart, packed2, ac, W1, b1, W2, b2, batch, gsumi);
    k_readout<<<1, 64, 0, stream>>>(gsumi, gcnt, Wfc, bfc, out);
}

// Round 13
// 215.174 us; speedup vs baseline: 1.6764x; 1.0241x over previous
//
#include <hip/hip_runtime.h>
#include <math.h>

#define N_NODES 100000
#define N_EDGES 3200000
#define N_GRAPHS 64
#define BW 512                               // nodes per bucket
#define LSH 9
#define LMASK 511u
#define NBUCK ((N_NODES + BW - 1) / BW)      // 196
#define CHUNK_E 8192
#define NCHUNK ((N_EDGES + CHUNK_E - 1) / CHUNK_E)  // 391
#define CAP_E 18432                          // per-bucket capacity in padded 'packed' (mean 16327, +16 sigma)
#define POOL_SCALE 1024.0f
#define POOL_INV (1.0f / 1024.0f)
#define SENT ((unsigned int)N_NODES << LSH)  // sentinel edge -> ac[N_NODES] == (0,0)

// ---- pass D (self-reserving; absorbs k_count and deletes k_scanc): ----
// per-chunk LDS hist over dst -> one global fetch_add per nonzero bucket ->
// scatter into the bucket's FIXED-CAPACITY region [b*CAP_E ...). After this
// kernel gcur[b] == exact bucket size. Bucket-confined writes keep the active
// write set at ~196 moving pointers — rounds 2/10: per-NODE cursors / random
// global atomics thrash the coherence point (100-200MB WRITE). Don't de-bucket.
__global__ void k_part(const int* __restrict__ src, const int* __restrict__ dst,
                       unsigned int* __restrict__ gcur, unsigned int* __restrict__ packed) {
    __shared__ unsigned int hist[NBUCK];
    __shared__ unsigned int sstart[NBUCK];
    for (int i = threadIdx.x; i < NBUCK; i += blockDim.x) hist[i] = 0u;
    __syncthreads();
    int e0 = blockIdx.x * CHUNK_E;
    int e1 = min(e0 + CHUNK_E, N_EDGES);
    for (int e = e0 + threadIdx.x; e < e1; e += blockDim.x)
        atomicAdd(&hist[dst[e] >> LSH], 1u);
    __syncthreads();
    for (int i = threadIdx.x; i < NBUCK; i += blockDim.x) {
        unsigned int h = hist[i];
        sstart[i] = h ? ((unsigned int)i * CAP_E + atomicAdd(&gcur[i], h)) : 0u;
        hist[i] = 0u;                        // reuse as scatter cursor
    }
    __syncthreads();
    for (int e = e0 + threadIdx.x; e < e1; e += blockDim.x) {
        int d = dst[e];
        int bk = d >> LSH;
        unsigned int pos = sstart[bk] + atomicAdd(&hist[bk], 1u);
        packed[pos] = ((unsigned int)src[e] << LSH) | ((unsigned int)d & LMASK);
    }
}

// ---- tiny scan: exact bucket sizes (gcur) -> contiguous base for packed2 ----
__global__ void k_scanp(const unsigned int* __restrict__ gcur, unsigned int* __restrict__ base) {
    __shared__ unsigned int sd[256];
    int t = threadIdx.x;
    unsigned int v = (t < NBUCK) ? gcur[t] : 0u;
    sd[t] = v;
    __syncthreads();
    for (int o = 1; o < 256; o <<= 1) {
        unsigned int tv = (t >= o) ? sd[t - o] : 0u;
        __syncthreads();
        sd[t] += tv;
        __syncthreads();
    }
    if (t < NBUCK) base[t] = sd[t] - v;
    if (t == 0) base[NBUCK] = N_EDGES;
}

// ---- pass E1: per-bucket histogram + scan -> rowstart, dinv, s ----
// Reads the bucket's padded region; writes contiguous rowstart from base[b].
// hist[t] IS node (b*BW+t)'s degree — dinv/s computed here.
__global__ void k_sorta(const unsigned int* __restrict__ gcur, const unsigned int* __restrict__ base,
                        const unsigned int* __restrict__ packed,
                        unsigned int* __restrict__ rowstart, const float* __restrict__ x,
                        float* __restrict__ dinv, float* __restrict__ s, float2* __restrict__ ac) {
    __shared__ unsigned int hist[BW];
    __shared__ unsigned int scan[BW];
    int b = blockIdx.x;
    unsigned int r0 = (unsigned int)b * CAP_E;
    unsigned int r1 = r0 + gcur[b];
    unsigned int wbase = base[b];
    if (threadIdx.x < BW) hist[threadIdx.x] = 0u;
    if (b == 0 && threadIdx.x == 0) ac[N_NODES] = make_float2(0.0f, 0.0f);  // k_l2 sentinel
    __syncthreads();
    for (unsigned int e = r0 + threadIdx.x; e < r1; e += blockDim.x)
        atomicAdd(&hist[packed[e] & LMASK], 1u);
    __syncthreads();
    if (threadIdx.x < BW) scan[threadIdx.x] = hist[threadIdx.x];
    __syncthreads();
    for (int o = 1; o < BW; o <<= 1) {
        unsigned int v = 0u;
        if (threadIdx.x < BW && threadIdx.x >= (unsigned)o) v = scan[threadIdx.x - o];
        __syncthreads();
        if (threadIdx.x < BW && threadIdx.x >= (unsigned)o) scan[threadIdx.x] += v;
        __syncthreads();
    }
    if (threadIdx.x < BW) {
        unsigned int deg = hist[threadIdx.x];
        rowstart[b * BW + threadIdx.x] = wbase + scan[threadIdx.x] - deg;
        int n = b * BW + threadIdx.x;
        if (n < N_NODES) {
            float di = 1.0f / sqrtf((float)(deg + 1u));  // +1 self-loop
            dinv[n] = di;
            s[n] = x[n] * di;
        }
    }
}

// ---- pass E2: scatter padded packed -> contiguous packed2, FUSED with layer 1 ----
// Cursors rebuilt from rowstart. Per edge, fsum[d] += s[src] (native ds_add_f32).
// Accumulation order is LDS-atomic-nondeterministic: same class as the edge
// order (already atomic); the int-quantized pooling absorbs it.
__global__ void k_sortb(const unsigned int* __restrict__ gcur, const unsigned int* __restrict__ base,
                        const unsigned int* __restrict__ packed,
                        const unsigned int* __restrict__ rowstart,
                        unsigned int* __restrict__ packed2,
                        const float* __restrict__ dinv, const float* __restrict__ s,
                        float2* __restrict__ ac) {
    __shared__ unsigned int cur[BW];
    __shared__ float fsum[BW];
    int b = blockIdx.x;
    unsigned int r0 = (unsigned int)b * CAP_E;
    unsigned int r1 = r0 + gcur[b];
    unsigned int wbase = base[b];
    if (threadIdx.x < BW) {
        cur[threadIdx.x] = rowstart[b * BW + threadIdx.x] - wbase;
        fsum[threadIdx.x] = 0.0f;
    }
    __syncthreads();
    for (unsigned int e = r0 + threadIdx.x; e < r1; e += blockDim.x) {
        unsigned int p = packed[e];
        unsigned int d = p & LMASK;
        unsigned int pos = wbase + atomicAdd(&cur[d], 1u);
        packed2[pos] = p;
        atomicAdd(&fsum[d], s[p >> LSH]);   // layer-1 neighbor sum (ds_add_f32, L2-resident gather)
    }
    __syncthreads();
    if (threadIdx.x < BW) {
        int n = b * BW + threadIdx.x;
        if (n < N_NODES) {
            float di = dinv[n];
            ac[n] = make_float2(di, di * di * (fsum[threadIdx.x] + s[n]));
        }
    }
}

// ---- graph node counts via binary search (no atomics) ----
__global__ void k_gcnt(const int* __restrict__ batch, float* __restrict__ gcnt) {
    __shared__ int lb[N_GRAPHS + 1];
    int b = threadIdx.x;
    if (b <= N_GRAPHS) {
        int lo = 0, hi = N_NODES;
        while (lo < hi) {
            int mid = (lo + hi) >> 1;
            if (batch[mid] < b) lo = mid + 1; else hi = mid;
        }
        lb[b] = lo;
    }
    __syncthreads();
    if (b < N_GRAPHS) gcnt[b] = (float)(lb[b + 1] - lb[b]);
}

// ---- layer 2: one 64-lane wave per node, lane j = column j ----
// ROUND-5 KERNEL VERBATIM — proven 36 VGPR, zero scratch, 54-56 µs, FETCH 10 MB.
// DO NOT EDIT THIS KERNEL'S BODY: rounds 6/7/8 each made small changes (packed
// math; prefetch+4 accumulators; even a 2-accumulator algebra tweak) and ALL
// tipped the register allocator into demoting w2c[32] to scratch — 100-310 MB
// of HBM scratch traffic, 2-3x kernel slowdown, and graph-replay-wide damage.
// The codegen sits exactly on a register-bucket boundary.
#define NPW 8

#define EDGE_PAIR(P) { \
    float4 q_ = Epair4[(P)]; \
    H += fmaxf(fmaf(q_.y, w1j, q_.x * b1j), 0.0f); \
    H += fmaxf(fmaf(q_.w, w1j, q_.z * b1j), 0.0f); }

#define BLOCK16(P0) { \
    EDGE_PAIR((P0) + 0) EDGE_PAIR((P0) + 1) EDGE_PAIR((P0) + 2) EDGE_PAIR((P0) + 3) \
    EDGE_PAIR((P0) + 4) EDGE_PAIR((P0) + 5) EDGE_PAIR((P0) + 6) EDGE_PAIR((P0) + 7) }

__global__ __launch_bounds__(256, 6)
void k_l2(const unsigned int* __restrict__ rowstart, const unsigned int* __restrict__ packed2,
          const float2* __restrict__ ac,
          const float* __restrict__ W1, const float* __restrict__ b1,
          const float* __restrict__ W2, const float* __restrict__ b2,
          const int* __restrict__ batch, int* __restrict__ gsumi) {
    __shared__ float Hrow[4][64];    // one 64-float row per wave; wave-private
    __shared__ float4 Ebuf[4][32];   // 64 (ax,ay) pairs per wave, read as float4 (2 edges/read)
    const int lane = threadIdx.x & 63;
    const int wv   = threadIdx.x >> 6;
    const int k    = lane & 31;     // output column for matvec/pool
    const int jh   = lane >> 5;     // which half of the 64-wide hidden dim this lane reduces
    const int j0   = jh * 32;

    const float w1j = W1[lane];
    const float b1j = b1[lane];
    const float b2k = b2[k];
    float w2c[32];
#pragma unroll
    for (int j = 0; j < 32; j++) w2c[j] = W2[(j0 + j) * 32 + k];

    float4* Epair4 = &Ebuf[wv][0];                 // wave-uniform base
    float2* Ewr    = (float2*)&Ebuf[wv][0];        // per-lane write slot

    int n0 = (blockIdx.x * 4 + wv) * NPW;
    float racc = 0.0f;
    int curg = -1;
    for (int i = 0; i < NPW; i++) {
        int n = n0 + i;
        if (n >= N_NODES) break;
        unsigned int rs = rowstart[n], re = rowstart[n + 1];
        float2 acn = ac[n];
        // self-loop contribution
        float H = fmaxf(fmaf(acn.y, w1j, acn.x * b1j), 0.0f);
        unsigned int e0 = rs;
        // full 64-slot batches (deg >= 64, rare at Poisson(32))
        while (e0 + 64u <= re) {
            unsigned int p = packed2[e0 + lane];     // all lanes valid
            Ewr[lane] = ac[p >> LSH];                // gather -> wave-private LDS (ds_write_b64)
            BLOCK16(0) BLOCK16(8) BLOCK16(16) BLOCK16(24)
            e0 += 64u;
        }
        unsigned int rem = re - e0;                  // 0..63
        if (rem) {
            unsigned int idx = e0 + lane;
            unsigned int p = SENT;                   // sentinel -> ac[N_NODES] == (0,0)
            if (idx < re) p = packed2[idx];          // exec-masked load, no OOB
            Ewr[lane] = ac[p >> LSH];
            switch ((rem + 15u) >> 4) {              // 1..4 blocks of 16 slots (8 pairs)
                case 4: BLOCK16(24); [[fallthrough]];
                case 3: BLOCK16(16); [[fallthrough]];
                case 2: BLOCK16(8);  [[fallthrough]];
                case 1: BLOCK16(0);
            }
        }
        // matvec: out_k = relu(dinv_n * (H . W2[:,k]) + b2[k])
        Hrow[wv][lane] = H;     // same-wave ds ordering: visible to this wave without barrier
        float accv = 0.0f;
#pragma unroll
        for (int jj = 0; jj < 8; jj++) {
            float4 hv = *(const float4*)&Hrow[wv][j0 + 4 * jj];
            accv += hv.x * w2c[4 * jj + 0] + hv.y * w2c[4 * jj + 1]
                  + hv.z * w2c[4 * jj + 2] + hv.w * w2c[4 * jj + 3];
        }
        accv += __shfl_xor(accv, 32);   // combine half-partials (width 64)
        float v = fmaxf(fmaf(acn.x, accv, b2k), 0.0f);
        int gb = batch[n];               // wave-uniform scalar load
        if (gb != curg) {
            if (curg >= 0 && jh == 0)
                atomicAdd(&gsumi[curg * 32 + k], __float2int_rn(racc * POOL_SCALE));
            racc = 0.0f; curg = gb;
        }
        racc += v;
    }
    if (curg >= 0 && jh == 0)
        atomicAdd(&gsumi[curg * 32 + k], __float2int_rn(racc * POOL_SCALE));
}

// ---- readout ----
__global__ void k_readout(const int* __restrict__ gsumi, const float* __restrict__ gcnt,
                          const float* __restrict__ Wfc, const float* __restrict__ bfc,
                          float* __restrict__ out) {
    int b = threadIdx.x;
    if (b < N_GRAPHS) {
        float inv = 1.0f / fmaxf(gcnt[b], 1.0f);
        float acc = bfc[0];
#pragma unroll
        for (int k = 0; k < 32; k++)
            acc += (float)gsumi[b * 32 + k] * POOL_INV * inv * Wfc[k];
        out[b] = 1.0f / (1.0f + expf(-acc));
    }
}

// ---- launch ----
extern "C" void kernel_launch(void* const* d_in, const int* in_sizes, int n_in,
                              void* d_out, int out_size, void* d_ws, size_t ws_size,
                              hipStream_t stream) {
    const float* x    = (const float*)d_in[0];
    const int*   ei   = (const int*)d_in[1];
    const int*   batch= (const int*)d_in[2];
    const float* W1   = (const float*)d_in[3];
    const float* b1   = (const float*)d_in[4];
    const float* W2   = (const float*)d_in[5];
    const float* b2   = (const float*)d_in[6];
    const float* Wfc  = (const float*)d_in[7];
    const float* bfc  = (const float*)d_in[8];
    float* out = (float*)d_out;

    const int* srcIdx = ei;
    const int* dstIdx = ei + N_EDGES;

    char* w = (char*)d_ws;
    unsigned int* gcur    = (unsigned int*)w; w += ((NBUCK + 64) & ~63) * 4;
    unsigned int* base    = (unsigned int*)w; w += ((NBUCK + 1 + 63) & ~63) * 4;
    unsigned int* packed  = (unsigned int*)w; w += (size_t)NBUCK * CAP_E * 4;   // padded bucket regions
    unsigned int* packed2 = (unsigned int*)w; w += (size_t)(N_EDGES + 64) * 4;  // contiguous
    unsigned int* rowstart= (unsigned int*)w; w += (size_t)(NBUCK * BW + 64) * 4;
    float* dinv = (float*)w;                  w += (size_t)N_NODES * 4;
    float* sbuf = (float*)w;                  w += (size_t)N_NODES * 4;
    float2* ac  = (float2*)w;                 w += (size_t)(N_NODES + 8) * 8;
    int* gsumi  = (int*)w;                    w += (size_t)N_GRAPHS * 32 * 4;
    float* gcnt = (float*)w;                  w += (size_t)N_GRAPHS * 4;

    hipMemsetAsync(gcur, 0, (size_t)NBUCK * 4, stream);
    hipMemsetAsync(gsumi, 0, (size_t)N_GRAPHS * 32 * 4, stream);

    k_part <<<NCHUNK, 512, 0, stream>>>(srcIdx, dstIdx, gcur, packed);
    k_scanp<<<1, 256, 0, stream>>>(gcur, base);
    k_sorta<<<NBUCK, 1024, 0, stream>>>(gcur, base, packed, rowstart, x, dinv, sbuf, ac);
    k_sortb<<<NBUCK, 1024, 0, stream>>>(gcur, base, packed, rowstart, packed2, dinv, sbuf, ac);
    k_gcnt <<<1, 128, 0, stream>>>(batch, gcnt);
    k_l2   <<<(N_NODES + 4 * NPW - 1) / (4 * NPW), 256, 0, stream>>>(rowstart, packed2, ac, W1, b1, W2, b2, batch, gsumi);
    k_readout<<<1, 64, 0, stream>>>(gsumi, gcnt, Wfc, bfc, out);
}

// Round 14
// 206.491 us; speedup vs baseline: 1.7469x; 1.0421x over previous
//
#include <hip/hip_runtime.h>
#include <math.h>

#define N_NODES 100000
#define N_EDGES 3200000
#define N_GRAPHS 64
#define BW 512                               // nodes per bucket
#define LSH 9
#define LMASK 511u
#define NBUCK ((N_NODES + BW - 1) / BW)      // 196
#define CHUNK_E 16384
#define NCHUNK ((N_EDGES + CHUNK_E - 1) / CHUNK_E)  // 196
#define CAP_E 18432                          // per-bucket capacity in padded 'packed' (mean 16327, +16 sigma)
#define POOL_SCALE 1024.0f
#define POOL_INV (1.0f / 1024.0f)
#define SENT ((unsigned int)N_NODES << LSH)  // sentinel edge -> ac[N_NODES] == (0,0)

// ---- pass D (self-reserving): per-chunk LDS hist over dst -> one global
// fetch_add per nonzero bucket -> scatter into the bucket's FIXED-CAPACITY
// region [b*CAP_E ...). After this kernel gcur[b] == exact bucket size.
// Bucket-confined writes keep the active write set at ~196 moving pointers —
// rounds 2/10: per-NODE cursors / random global atomics thrash the coherence
// point (100-200MB WRITE). Don't de-bucket. r14: CHUNK_E 8192->16384 @1024thr
// (same 3136 waves, doubled write-run length ~84 edges = 2.6 lines).
__global__ void k_part(const int* __restrict__ src, const int* __restrict__ dst,
                       unsigned int* __restrict__ gcur, unsigned int* __restrict__ packed) {
    __shared__ unsigned int hist[NBUCK];
    __shared__ unsigned int sstart[NBUCK];
    for (int i = threadIdx.x; i < NBUCK; i += blockDim.x) hist[i] = 0u;
    __syncthreads();
    int e0 = blockIdx.x * CHUNK_E;
    int e1 = min(e0 + CHUNK_E, N_EDGES);
    for (int e = e0 + threadIdx.x; e < e1; e += blockDim.x)
        atomicAdd(&hist[dst[e] >> LSH], 1u);
    __syncthreads();
    for (int i = threadIdx.x; i < NBUCK; i += blockDim.x) {
        unsigned int h = hist[i];
        sstart[i] = h ? ((unsigned int)i * CAP_E + atomicAdd(&gcur[i], h)) : 0u;
        hist[i] = 0u;                        // reuse as scatter cursor
    }
    __syncthreads();
    for (int e = e0 + threadIdx.x; e < e1; e += blockDim.x) {
        int d = dst[e];
        int bk = d >> LSH;
        unsigned int pos = sstart[bk] + atomicAdd(&hist[bk], 1u);
        packed[pos] = ((unsigned int)src[e] << LSH) | ((unsigned int)d & LMASK);
    }
}

// ---- pass E1: per-bucket histogram + scan -> rowstart, dinv, s ----
// r14: absorbs k_scanp — each block redundantly scans the 196 bucket sizes in
// LDS (round-6 pattern) and takes its own exclusive prefix as the contiguous
// write base. hist[t] IS node (b*BW+t)'s degree — dinv/s computed here.
__global__ void k_sorta(const unsigned int* __restrict__ gcur,
                        const unsigned int* __restrict__ packed,
                        unsigned int* __restrict__ rowstart, const float* __restrict__ x,
                        float* __restrict__ dinv, float* __restrict__ s, float2* __restrict__ ac) {
    __shared__ unsigned int hist[BW];
    __shared__ unsigned int scan[BW];
    __shared__ unsigned int sdp[256];
    __shared__ unsigned int swbase;
    int b = blockIdx.x;
    int t = threadIdx.x;
    // phase 0: redundant scan of gcur[0..NBUCK) -> this bucket's exclusive base
    unsigned int gv = 0u;
    if (t < 256) { gv = (t < NBUCK) ? gcur[t] : 0u; sdp[t] = gv; }
    if (t < BW) hist[t] = 0u;
    if (b == 0 && t == 0) ac[N_NODES] = make_float2(0.0f, 0.0f);  // k_l2 sentinel
    __syncthreads();
    for (int o = 1; o < 256; o <<= 1) {
        unsigned int v = 0u;
        if (t < 256 && t >= o) v = sdp[t - o];
        __syncthreads();
        if (t < 256 && t >= o) sdp[t] += v;
        __syncthreads();
    }
    if (t == b) swbase = sdp[t] - gv;
    __syncthreads();
    unsigned int wbase = swbase;
    unsigned int r0 = (unsigned int)b * CAP_E;
    unsigned int r1 = r0 + gcur[b];
    for (unsigned int e = r0 + t; e < r1; e += blockDim.x)
        atomicAdd(&hist[packed[e] & LMASK], 1u);
    __syncthreads();
    if (t < BW) scan[t] = hist[t];
    __syncthreads();
    for (int o = 1; o < BW; o <<= 1) {
        unsigned int v = 0u;
        if (t < BW && t >= o) v = scan[t - o];
        __syncthreads();
        if (t < BW && t >= o) scan[t] += v;
        __syncthreads();
    }
    if (t < BW) {
        unsigned int deg = hist[t];
        rowstart[b * BW + t] = wbase + scan[t] - deg;
        int n = b * BW + t;
        if (n < N_NODES) {
            float di = 1.0f / sqrtf((float)(deg + 1u));  // +1 self-loop
            dinv[n] = di;
            s[n] = x[n] * di;
        }
    }
}

// ---- pass E2: scatter padded packed -> contiguous packed2, FUSED with layer 1 ----
// r14: ABSOLUTE cursors from rowstart (no base dependency). Per edge,
// fsum[d] += s[src] (native ds_add_f32). Accumulation order is
// LDS-atomic-nondeterministic: same class as the edge order (already atomic);
// the int-quantized pooling absorbs it.
__global__ void k_sortb(const unsigned int* __restrict__ gcur,
                        const unsigned int* __restrict__ packed,
                        const unsigned int* __restrict__ rowstart,
                        unsigned int* __restrict__ packed2,
                        const float* __restrict__ dinv, const float* __restrict__ s,
                        float2* __restrict__ ac) {
    __shared__ unsigned int cur[BW];
    __shared__ float fsum[BW];
    int b = blockIdx.x;
    unsigned int r0 = (unsigned int)b * CAP_E;
    unsigned int r1 = r0 + gcur[b];
    if (threadIdx.x < BW) {
        cur[threadIdx.x] = rowstart[b * BW + threadIdx.x];   // absolute position
        fsum[threadIdx.x] = 0.0f;
    }
    __syncthreads();
    for (unsigned int e = r0 + threadIdx.x; e < r1; e += blockDim.x) {
        unsigned int p = packed[e];
        unsigned int d = p & LMASK;
        unsigned int pos = atomicAdd(&cur[d], 1u);
        packed2[pos] = p;
        atomicAdd(&fsum[d], s[p >> LSH]);   // layer-1 neighbor sum (ds_add_f32, L2-resident gather)
    }
    __syncthreads();
    if (threadIdx.x < BW) {
        int n = b * BW + threadIdx.x;
        if (n < N_NODES) {
            float di = dinv[n];
            ac[n] = make_float2(di, di * di * (fsum[threadIdx.x] + s[n]));
        }
    }
}

// ---- layer 2: one 64-lane wave per node, lane j = column j ----
// ROUND-5 KERNEL VERBATIM — proven 36 VGPR, zero scratch, 54-56 µs, FETCH 10 MB.
// DO NOT EDIT THIS KERNEL'S BODY: rounds 6/7/8 each made small changes (packed
// math; prefetch+4 accumulators; even a 2-accumulator algebra tweak) and ALL
// tipped the register allocator into demoting w2c[32] to scratch — 100-310 MB
// of HBM scratch traffic, 2-3x kernel slowdown, and graph-replay-wide damage.
// The codegen sits exactly on a register-bucket boundary.
#define NPW 8

#define EDGE_PAIR(P) { \
    float4 q_ = Epair4[(P)]; \
    H += fmaxf(fmaf(q_.y, w1j, q_.x * b1j), 0.0f); \
    H += fmaxf(fmaf(q_.w, w1j, q_.z * b1j), 0.0f); }

#define BLOCK16(P0) { \
    EDGE_PAIR((P0) + 0) EDGE_PAIR((P0) + 1) EDGE_PAIR((P0) + 2) EDGE_PAIR((P0) + 3) \
    EDGE_PAIR((P0) + 4) EDGE_PAIR((P0) + 5) EDGE_PAIR((P0) + 6) EDGE_PAIR((P0) + 7) }

__global__ __launch_bounds__(256, 6)
void k_l2(const unsigned int* __restrict__ rowstart, const unsigned int* __restrict__ packed2,
          const float2* __restrict__ ac,
          const float* __restrict__ W1, const float* __restrict__ b1,
          const float* __restrict__ W2, const float* __restrict__ b2,
          const int* __restrict__ batch, int* __restrict__ gsumi) {
    __shared__ float Hrow[4][64];    // one 64-float row per wave; wave-private
    __shared__ float4 Ebuf[4][32];   // 64 (ax,ay) pairs per wave, read as float4 (2 edges/read)
    const int lane = threadIdx.x & 63;
    const int wv   = threadIdx.x >> 6;
    const int k    = lane & 31;     // output column for matvec/pool
    const int jh   = lane >> 5;     // which half of the 64-wide hidden dim this lane reduces
    const int j0   = jh * 32;

    const float w1j = W1[lane];
    const float b1j = b1[lane];
    const float b2k = b2[k];
    float w2c[32];
#pragma unroll
    for (int j = 0; j < 32; j++) w2c[j] = W2[(j0 + j) * 32 + k];

    float4* Epair4 = &Ebuf[wv][0];                 // wave-uniform base
    float2* Ewr    = (float2*)&Ebuf[wv][0];        // per-lane write slot

    int n0 = (blockIdx.x * 4 + wv) * NPW;
    float racc = 0.0f;
    int curg = -1;
    for (int i = 0; i < NPW; i++) {
        int n = n0 + i;
        if (n >= N_NODES) break;
        unsigned int rs = rowstart[n], re = rowstart[n + 1];
        float2 acn = ac[n];
        // self-loop contribution
        float H = fmaxf(fmaf(acn.y, w1j, acn.x * b1j), 0.0f);
        unsigned int e0 = rs;
        // full 64-slot batches (deg >= 64, rare at Poisson(32))
        while (e0 + 64u <= re) {
            unsigned int p = packed2[e0 + lane];     // all lanes valid
            Ewr[lane] = ac[p >> LSH];                // gather -> wave-private LDS (ds_write_b64)
            BLOCK16(0) BLOCK16(8) BLOCK16(16) BLOCK16(24)
            e0 += 64u;
        }
        unsigned int rem = re - e0;                  // 0..63
        if (rem) {
            unsigned int idx = e0 + lane;
            unsigned int p = SENT;                   // sentinel -> ac[N_NODES] == (0,0)
            if (idx < re) p = packed2[idx];          // exec-masked load, no OOB
            Ewr[lane] = ac[p >> LSH];
            switch ((rem + 15u) >> 4) {              // 1..4 blocks of 16 slots (8 pairs)
                case 4: BLOCK16(24); [[fallthrough]];
                case 3: BLOCK16(16); [[fallthrough]];
                case 2: BLOCK16(8);  [[fallthrough]];
                case 1: BLOCK16(0);
            }
        }
        // matvec: out_k = relu(dinv_n * (H . W2[:,k]) + b2[k])
        Hrow[wv][lane] = H;     // same-wave ds ordering: visible to this wave without barrier
        float accv = 0.0f;
#pragma unroll
        for (int jj = 0; jj < 8; jj++) {
            float4 hv = *(const float4*)&Hrow[wv][j0 + 4 * jj];
            accv += hv.x * w2c[4 * jj + 0] + hv.y * w2c[4 * jj + 1]
                  + hv.z * w2c[4 * jj + 2] + hv.w * w2c[4 * jj + 3];
        }
        accv += __shfl_xor(accv, 32);   // combine half-partials (width 64)
        float v = fmaxf(fmaf(acn.x, accv, b2k), 0.0f);
        int gb = batch[n];               // wave-uniform scalar load
        if (gb != curg) {
            if (curg >= 0 && jh == 0)
                atomicAdd(&gsumi[curg * 32 + k], __float2int_rn(racc * POOL_SCALE));
            racc = 0.0f; curg = gb;
        }
        racc += v;
    }
    if (curg >= 0 && jh == 0)
        atomicAdd(&gsumi[curg * 32 + k], __float2int_rn(racc * POOL_SCALE));
}

// ---- readout (r14: absorbs k_gcnt's binary search) ----
__global__ void k_readout(const int* __restrict__ gsumi, const int* __restrict__ batch,
                          const float* __restrict__ Wfc, const float* __restrict__ bfc,
                          float* __restrict__ out) {
    __shared__ int lb[N_GRAPHS + 1];
    int b = threadIdx.x;
    if (b <= N_GRAPHS) {
        int lo = 0, hi = N_NODES;
        while (lo < hi) {
            int mid = (lo + hi) >> 1;
            if (batch[mid] < b) lo = mid + 1; else hi = mid;
        }
        lb[b] = lo;
    }
    __syncthreads();
    if (b < N_GRAPHS) {
        float inv = 1.0f / fmaxf((float)(lb[b + 1] - lb[b]), 1.0f);
        float acc = bfc[0];
#pragma unroll
        for (int k = 0; k < 32; k++)
            acc += (float)gsumi[b * 32 + k] * POOL_INV * inv * Wfc[k];
        out[b] = 1.0f / (1.0f + expf(-acc));
    }
}

// ---- launch ----
extern "C" void kernel_launch(void* const* d_in, const int* in_sizes, int n_in,
                              void* d_out, int out_size, void* d_ws, size_t ws_size,
                              hipStream_t stream) {
    const float* x    = (const float*)d_in[0];
    const int*   ei   = (const int*)d_in[1];
    const int*   batch= (const int*)d_in[2];
    const float* W1   = (const float*)d_in[3];
    const float* b1   = (const float*)d_in[4];
    const float* W2   = (const float*)d_in[5];
    const float* b2   = (const float*)d_in[6];
    const float* Wfc  = (const float*)d_in[7];
    const float* bfc  = (const float*)d_in[8];
    float* out = (float*)d_out;

    const int* srcIdx = ei;
    const int* dstIdx = ei + N_EDGES;

    char* w = (char*)d_ws;
    unsigned int* gcur    = (unsigned int*)w; w += ((NBUCK + 64) & ~63) * 4;
    unsigned int* packed  = (unsigned int*)w; w += (size_t)NBUCK * CAP_E * 4;   // padded bucket regions
    unsigned int* packed2 = (unsigned int*)w; w += (size_t)(N_EDGES + 64) * 4;  // contiguous
    unsigned int* rowstart= (unsigned int*)w; w += (size_t)(NBUCK * BW + 64) * 4;
    float* dinv = (float*)w;                  w += (size_t)N_NODES * 4;
    float* sbuf = (float*)w;                  w += (size_t)N_NODES * 4;
    float2* ac  = (float2*)w;                 w += (size_t)(N_NODES + 8) * 8;
    int* gsumi  = (int*)w;                    w += (size_t)N_GRAPHS * 32 * 4;

    hipMemsetAsync(gcur, 0, (size_t)NBUCK * 4, stream);
    hipMemsetAsync(gsumi, 0, (size_t)N_GRAPHS * 32 * 4, stream);

    k_part <<<NCHUNK, 1024, 0, stream>>>(srcIdx, dstIdx, gcur, packed);
    k_sorta<<<NBUCK, 1024, 0, stream>>>(gcur, packed, rowstart, x, dinv, sbuf, ac);
    k_sortb<<<NBUCK, 1024, 0, stream>>>(gcur, packed, rowstart, packed2, dinv, sbuf, ac);
    k_l2   <<<(N_NODES + 4 * NPW - 1) / (4 * NPW), 256, 0, stream>>>(rowstart, packed2, ac, W1, b1, W2, b2, batch, gsumi);
    k_readout<<<1, 128, 0, stream>>>(gsumi, batch, Wfc, bfc, out);
}